// Round 6
// baseline (570.178 us; speedup 1.0000x reference)
//
#include <hip/hip_runtime.h>
#include <hip/hip_bf16.h>
#include <math.h>

// ---------------------------------------------------------------------------
// ChebNet (K=3) two-layer forward, restructured:
//   cheb(x,W) = x@W0 - x@W2 + P(x@W1 + 2*P(x@W2)) + b,  P = edge scatter-sum
// P applied in output feature space (64 then 40 dims).
// Edge scatter converted to CSR-by-dst gather (hierarchical scan build).
// CSR records packed (src,norm) 8B; prop unrolls gathers 8-wide for MLP.
// All prop gather inputs stored bf16 (halves random-gather traffic).
// GEMM1: fp32 A via bf16 hi/lo split (3 MFMA); GEMM2: bf16 A exact (2 MFMA).
// ---------------------------------------------------------------------------

#define FIN1 128
#define HID 64
#define NCLS 40
#define UNR 8

typedef __attribute__((ext_vector_type(8))) short sx8;
typedef __attribute__((ext_vector_type(4))) float fx4;

__device__ inline unsigned short f2bf(float f) {
    unsigned u = __float_as_uint(f);
    unsigned r = (u + 0x7FFF + ((u >> 16) & 1)) >> 16;  // RNE
    return (unsigned short)r;
}
__device__ inline float bf2f(unsigned short h) {
    return __uint_as_float((unsigned)h << 16);
}

__global__ void k_count(const int* __restrict__ dst, int E, int* __restrict__ count) {
    int e = blockIdx.x * blockDim.x + threadIdx.x;
    if (e < E) atomicAdd(&count[dst[e]], 1);
}

// ---- hierarchical exclusive scan over count[N] ----
template <int EPT>
__global__ __launch_bounds__(256) void k_scan_part(const int* __restrict__ count, int N,
                                                   int* __restrict__ partial) {
    __shared__ int ws[4];
    int t = threadIdx.x;
    int lane = t & 63, w = t >> 6;
    int idx0 = blockIdx.x * 256 * EPT + t * EPT;
    int s = 0;
#pragma unroll
    for (int i = 0; i < EPT; ++i) {
        int idx = idx0 + i;
        if (idx < N) s += count[idx];
    }
#pragma unroll
    for (int d = 1; d < 64; d <<= 1) s += __shfl_xor(s, d);
    if (lane == 0) ws[w] = s;
    __syncthreads();
    if (t == 0) partial[blockIdx.x] = ws[0] + ws[1] + ws[2] + ws[3];
}

__global__ __launch_bounds__(256) void k_scan_mid(int* __restrict__ partial, int nb) {
    __shared__ int s[256];
    int t = threadIdx.x;
    int orig = (t < nb) ? partial[t] : 0;
    s[t] = orig;
    __syncthreads();
    for (int d = 1; d < 256; d <<= 1) {
        int v = (t >= d) ? s[t - d] : 0;
        __syncthreads();
        s[t] += v;
        __syncthreads();
    }
    if (t < nb) partial[t] = s[t] - orig;  // exclusive
}

template <int EPT>
__global__ __launch_bounds__(256) void k_scan_final(const int* __restrict__ count, int N,
                                                    const int* __restrict__ partial,
                                                    int* __restrict__ row_ptr,
                                                    int* __restrict__ cursor,
                                                    float* __restrict__ dis) {
    __shared__ int wsum[4];
    int t = threadIdx.x;
    int lane = t & 63, w = t >> 6;
    int idx0 = blockIdx.x * 256 * EPT + t * EPT;
    int c[EPT];
    int s = 0;
#pragma unroll
    for (int i = 0; i < EPT; ++i) {
        int idx = idx0 + i;
        c[i] = (idx < N) ? count[idx] : 0;
        s += c[i];
    }
    int incl = s;
#pragma unroll
    for (int d = 1; d < 64; d <<= 1) {
        int u = __shfl_up(incl, d);
        if (lane >= d) incl += u;
    }
    if (lane == 63) wsum[w] = incl;
    __syncthreads();
    int woff = 0;
    for (int i = 0; i < w; ++i) woff += wsum[i];
    int off = partial[blockIdx.x] + woff + (incl - s);
#pragma unroll
    for (int i = 0; i < EPT; ++i) {
        int idx = idx0 + i;
        if (idx < N) {
            row_ptr[idx] = off;
            cursor[idx] = off;
            dis[idx] = (c[i] > 0) ? rsqrtf((float)c[i]) : 0.0f;
            off += c[i];
            if (idx == N - 1) row_ptr[N] = off;
        }
    }
}

__global__ void k_fill(const int* __restrict__ src, const int* __restrict__ dst, int E,
                       const float* __restrict__ dis, int* __restrict__ cursor,
                       int2* __restrict__ csrp) {
    int e = blockIdx.x * blockDim.x + threadIdx.x;
    if (e < E) {
        int s = src[e];
        int d = dst[e];
        int pos = atomicAdd(&cursor[d], 1);
        csrp[pos] = make_int2(s, __float_as_int(-dis[s] * dis[d]));
    }
}

// Pre-swizzle W[3][FIN][FOE] (fp32) into MFMA B-fragment layout, hi/lo bf16.
template <int NS, int T, int FIN, int FOE>
__global__ void k_wprep(const float* __restrict__ W, unsigned short* __restrict__ hi,
                        unsigned short* __restrict__ lo) {
    int idx = blockIdx.x * 256 + threadIdx.x;
    constexpr int total = NS * T * 64 * 8;
    if (idx >= total) return;
    int i = idx & 7;
    int l = (idx >> 3) & 63;
    int t = (idx >> 9) % T;
    int s = idx / (512 * T);
    int k = s * 32 + (l >> 4) * 8 + i;
    int col = t * 16 + (l & 15);
    float w = 0.0f;
    if (col < 3 * FOE) {
        int m = col / FOE;
        int c = col - m * FOE;
        w = W[((size_t)m * FIN + k) * FOE + c];
    }
    unsigned short h = f2bf(w);
    hi[idx] = h;
    lo[idx] = f2bf(w - bf2f(h));
}

// MFMA GEMM, fp32 A (hi/lo split, 3 MFMA): C{0,1,2}= A@W[m]; C2 also as bf16.
template <int FIN, int T, int NS, int FOE>
__global__ __launch_bounds__(256, 3) void k_gemm_mfma(
    const float* __restrict__ A, const unsigned short* __restrict__ Whi,
    const unsigned short* __restrict__ Wlo, float* __restrict__ C0,
    float* __restrict__ C1, float* __restrict__ C2,
    unsigned short* __restrict__ C2h, int N) {
    int tid = threadIdx.x;
    int w = tid >> 6, l = tid & 63;
    int row0 = blockIdx.x * 128 + w * 32;
    int rl = l & 15, kg = l >> 4;

    fx4 acc[2][T];
#pragma unroll
    for (int rt = 0; rt < 2; ++rt)
#pragma unroll
        for (int t = 0; t < T; ++t) acc[rt][t] = (fx4)0.0f;

    for (int s = 0; s < NS; ++s) {
        int k0 = s * 32 + kg * 8;
        sx8 ahi[2], alo[2];
#pragma unroll
        for (int rt = 0; rt < 2; ++rt) {
            int r = min(row0 + rt * 16 + rl, N - 1);
            const fx4* ap = (const fx4*)(A + (size_t)r * FIN + k0);
            fx4 a0 = ap[0];
            fx4 a1 = ap[1];
#pragma unroll
            for (int j = 0; j < 4; ++j) {
                unsigned short h0 = f2bf(a0[j]);
                unsigned short h1 = f2bf(a1[j]);
                ahi[rt][j] = (short)h0;
                ahi[rt][j + 4] = (short)h1;
                alo[rt][j] = (short)f2bf(a0[j] - bf2f(h0));
                alo[rt][j + 4] = (short)f2bf(a1[j] - bf2f(h1));
            }
        }
        const sx8* wh = (const sx8*)(Whi + ((size_t)(s * T) * 64 + l) * 8);
        const sx8* wl = (const sx8*)(Wlo + ((size_t)(s * T) * 64 + l) * 8);
#pragma unroll
        for (int t = 0; t < T; ++t) {
            sx8 bh = wh[t * 64];
            sx8 bl = wl[t * 64];
#pragma unroll
            for (int rt = 0; rt < 2; ++rt) {
                acc[rt][t] = __builtin_amdgcn_mfma_f32_16x16x32_bf16(ahi[rt], bh, acc[rt][t], 0, 0, 0);
                acc[rt][t] = __builtin_amdgcn_mfma_f32_16x16x32_bf16(ahi[rt], bl, acc[rt][t], 0, 0, 0);
                acc[rt][t] = __builtin_amdgcn_mfma_f32_16x16x32_bf16(alo[rt], bh, acc[rt][t], 0, 0, 0);
            }
        }
    }

#pragma unroll
    for (int rt = 0; rt < 2; ++rt)
#pragma unroll
        for (int t = 0; t < T; ++t) {
            int col = t * 16 + rl;
            int m = col / FOE;
            int cc = col - m * FOE;
            if (m < 3) {
                float* Cm = (m == 0) ? C0 : ((m == 1) ? C1 : C2);
#pragma unroll
                for (int j = 0; j < 4; ++j) {
                    int r = row0 + rt * 16 + kg * 4 + j;
                    if (r < N) {
                        Cm[(size_t)r * FOE + cc] = acc[rt][t][j];
                        if (m == 2) C2h[(size_t)r * FOE + cc] = f2bf(acc[rt][t][j]);
                    }
                }
            }
        }
}

// MFMA GEMM, bf16 A (exact, 2 MFMA): C{0,1,2} = A@W[m]; C2 also as bf16.
template <int FIN, int T, int NS, int FOE>
__global__ __launch_bounds__(256, 3) void k_gemm_mfma_bf(
    const unsigned short* __restrict__ A, const unsigned short* __restrict__ Whi,
    const unsigned short* __restrict__ Wlo, float* __restrict__ C0,
    float* __restrict__ C1, float* __restrict__ C2,
    unsigned short* __restrict__ C2h, int N) {
    int tid = threadIdx.x;
    int w = tid >> 6, l = tid & 63;
    int row0 = blockIdx.x * 128 + w * 32;
    int rl = l & 15, kg = l >> 4;

    fx4 acc[2][T];
#pragma unroll
    for (int rt = 0; rt < 2; ++rt)
#pragma unroll
        for (int t = 0; t < T; ++t) acc[rt][t] = (fx4)0.0f;

    for (int s = 0; s < NS; ++s) {
        int k0 = s * 32 + kg * 8;
        sx8 a[2];
#pragma unroll
        for (int rt = 0; rt < 2; ++rt) {
            int r = min(row0 + rt * 16 + rl, N - 1);
            a[rt] = *(const sx8*)(A + (size_t)r * FIN + k0);
        }
        const sx8* wh = (const sx8*)(Whi + ((size_t)(s * T) * 64 + l) * 8);
        const sx8* wl = (const sx8*)(Wlo + ((size_t)(s * T) * 64 + l) * 8);
#pragma unroll
        for (int t = 0; t < T; ++t) {
            sx8 bh = wh[t * 64];
            sx8 bl = wl[t * 64];
#pragma unroll
            for (int rt = 0; rt < 2; ++rt) {
                acc[rt][t] = __builtin_amdgcn_mfma_f32_16x16x32_bf16(a[rt], bh, acc[rt][t], 0, 0, 0);
                acc[rt][t] = __builtin_amdgcn_mfma_f32_16x16x32_bf16(a[rt], bl, acc[rt][t], 0, 0, 0);
            }
        }
    }

#pragma unroll
    for (int rt = 0; rt < 2; ++rt)
#pragma unroll
        for (int t = 0; t < T; ++t) {
            int col = t * 16 + rl;
            int m = col / FOE;
            int cc = col - m * FOE;
            if (m < 3) {
                float* Cm = (m == 0) ? C0 : ((m == 1) ? C1 : C2);
#pragma unroll
                for (int j = 0; j < 4; ++j) {
                    int r = row0 + rt * 16 + kg * 4 + j;
                    if (r < N) {
                        Cm[(size_t)r * FOE + cc] = acc[rt][t][j];
                        if (m == 2) C2h[(size_t)r * FOE + cc] = f2bf(acc[rt][t][j]);
                    }
                }
            }
        }
}

// CSR gather-prop with fused epilogue. One 64-lane wave per dst node, lane=feature.
// Gather input is bf16 (halves random-read traffic); o0/o1 read fp32 coalesced.
// MODE 0: outh = bf16(o0 + 2*acc)
// MODE 1: outh = bf16(relu(o0 - o1 + acc + bias[f]))
// MODE 2: outf = log_softmax(o0 - o1 + acc + bias[f]) over F classes
template <int F, int MODE>
__global__ void k_prop(const int* __restrict__ row_ptr, const int2* __restrict__ csrp,
                       const unsigned short* __restrict__ in,
                       const float* __restrict__ o0, const float* __restrict__ o1,
                       const float* __restrict__ bias,
                       unsigned short* __restrict__ outh,
                       float* __restrict__ outf, int N) {
    int wid = (blockIdx.x * blockDim.x + threadIdx.x) >> 6;
    int lane = threadIdx.x & 63;
    if (wid >= N) return;
    int beg = row_ptr[wid];
    int end = row_ptr[wid + 1];
    float acc = 0.0f;
    for (int j = beg; j < end; j += UNR) {
        int ss[UNR];
        float ww[UNR];
#pragma unroll
        for (int i = 0; i < UNR; ++i) {
            int2 e = csrp[j + i];  // wave-uniform broadcast load (pad-safe)
            ss[i] = e.x;
            ww[i] = (j + i < end) ? __int_as_float(e.y) : 0.0f;
        }
#pragma unroll
        for (int i = 0; i < UNR; ++i) {
            float v = (lane < F) ? bf2f(in[(size_t)ss[i] * F + lane]) : 0.0f;
            acc = fmaf(ww[i], v, acc);
        }
    }
    size_t o = (size_t)wid * F + lane;
    if (MODE == 0) {
        if (lane < F) outh[o] = f2bf(o0[o] + 2.0f * acc);
    } else if (MODE == 1) {
        if (lane < F) {
            float z = o0[o] - o1[o] + acc + bias[lane];
            outh[o] = f2bf(fmaxf(z, 0.0f));
        }
    } else {
        float z = (lane < F) ? (o0[o] - o1[o] + acc + bias[lane]) : -INFINITY;
        float m = z;
#pragma unroll
        for (int d = 32; d; d >>= 1) m = fmaxf(m, __shfl_xor(m, d));
        float e = (lane < F) ? expf(z - m) : 0.0f;
        float l = e;
#pragma unroll
        for (int d = 32; d; d >>= 1) l += __shfl_xor(l, d);
        if (lane < F) outf[o] = z - m - logf(l);
    }
}

extern "C" void kernel_launch(void* const* d_in, const int* in_sizes, int n_in,
                              void* d_out, int out_size, void* d_ws, size_t ws_size,
                              hipStream_t stream) {
    const float* x = (const float*)d_in[0];
    const int* ei = (const int*)d_in[1];
    const float* W1 = (const float*)d_in[2];
    const float* b1 = (const float*)d_in[3];
    const float* W2 = (const float*)d_in[4];
    const float* b2 = (const float*)d_in[5];
    float* out = (float*)d_out;

    const int N = in_sizes[0] / FIN1;  // 100000
    const int E = in_sizes[1] / 2;     // 1600000
    const int* src = ei;
    const int* dst = ei + E;

    // workspace carve (256B aligned)
    char* p = (char*)d_ws;
    auto alloc = [&](size_t bytes) -> void* {
        void* r = (void*)p;
        p += (bytes + 255) & ~(size_t)255;
        return r;
    };
    int* count = (int*)alloc((size_t)N * 4);
    int* row_ptr = (int*)alloc((size_t)(N + 1) * 4);
    int* cursor = (int*)alloc((size_t)N * 4);
    float* dis = (float*)alloc((size_t)N * 4);
    int* partial = (int*)alloc(256 * 4);
    int2* csrp = (int2*)alloc(((size_t)E + UNR) * 8);  // packed (src, norm) + pad
    float* buf0 = (float*)alloc((size_t)N * HID * 4);   // c0 / d0
    float* buf1 = (float*)alloc((size_t)N * HID * 4);   // ca / da
    float* buf2 = (float*)alloc((size_t)N * HID * 4);   // cb / db (fp32, o1 use)
    unsigned short* buf2h = (unsigned short*)alloc((size_t)N * HID * 2);  // cb/db bf16
    unsigned short* buf3h = (unsigned short*)alloc((size_t)N * HID * 2);  // s/s2 bf16
    unsigned short* buf4h = (unsigned short*)alloc((size_t)N * HID * 2);  // h bf16
    // W fragment buffers (hi/lo bf16, B-frag layout)
    constexpr int W1FRAG = 4 * 12 * 64 * 8;  // 24576
    constexpr int W2FRAG = 2 * 8 * 64 * 8;   // 8192
    unsigned short* wf1h = (unsigned short*)alloc((size_t)W1FRAG * 2);
    unsigned short* wf1l = (unsigned short*)alloc((size_t)W1FRAG * 2);
    unsigned short* wf2h = (unsigned short*)alloc((size_t)W2FRAG * 2);
    unsigned short* wf2l = (unsigned short*)alloc((size_t)W2FRAG * 2);

    const int be = (E + 255) / 256;
    const int bg = (N + 127) / 128;       // MFMA gemm blocks (BM=128)
    const int bp = (N * 64 + 255) / 256;  // one wave per node
    constexpr int EPB = 256 * 8;
    const int nb = (N + EPB - 1) / EPB;   // 49 blocks for N=100000

    // ---- W fragment prep (independent of graph) ----
    k_wprep<4, 12, FIN1, HID><<<(W1FRAG + 255) / 256, 256, 0, stream>>>(W1, wf1h, wf1l);
    k_wprep<2, 8, HID, NCLS><<<(W2FRAG + 255) / 256, 256, 0, stream>>>(W2, wf2h, wf2l);

    // ---- graph structure: degree, CSR, norm ----
    hipMemsetAsync(count, 0, (size_t)N * 4, stream);
    hipMemsetAsync(csrp + E, 0, (size_t)UNR * 8, stream);  // zero pad records
    k_count<<<be, 256, 0, stream>>>(dst, E, count);
    k_scan_part<8><<<nb, 256, 0, stream>>>(count, N, partial);
    k_scan_mid<<<1, 256, 0, stream>>>(partial, nb);
    k_scan_final<8><<<nb, 256, 0, stream>>>(count, N, partial, row_ptr, cursor, dis);
    k_fill<<<be, 256, 0, stream>>>(src, dst, E, dis, cursor, csrp);

    // ---- layer 1: x[N,128] -> h[N,64] ----
    k_gemm_mfma<FIN1, 12, 4, HID><<<bg, 256, 0, stream>>>(x, wf1h, wf1l, buf0, buf1,
                                                          buf2, buf2h, N);
    // s = ca + 2*P(cb)
    k_prop<HID, 0><<<bp, 256, 0, stream>>>(row_ptr, csrp, buf2h, buf1, nullptr, nullptr,
                                           buf3h, nullptr, N);
    // h = relu(c0 - cb + P(s) + b1)
    k_prop<HID, 1><<<bp, 256, 0, stream>>>(row_ptr, csrp, buf3h, buf0, buf2, b1,
                                           buf4h, nullptr, N);

    // ---- layer 2: h[N,64] -> out[N,40] ----
    k_gemm_mfma_bf<HID, 8, 2, NCLS><<<bg, 256, 0, stream>>>(buf4h, wf2h, wf2l, buf0,
                                                            buf1, buf2, buf2h, N);
    // s2 = da + 2*P(db)
    k_prop<NCLS, 0><<<bp, 256, 0, stream>>>(row_ptr, csrp, buf2h, buf1, nullptr, nullptr,
                                            buf3h, nullptr, N);
    // out = log_softmax(d0 - db + P(s2) + b2)
    k_prop<NCLS, 2><<<bp, 256, 0, stream>>>(row_ptr, csrp, buf3h, buf0, buf2, b2,
                                            nullptr, out, N);
}

// Round 7
// 409.819 us; speedup vs baseline: 1.3913x; 1.3913x over previous
//
#include <hip/hip_runtime.h>
#include <hip/hip_bf16.h>
#include <math.h>

// ---------------------------------------------------------------------------
// ChebNet (K=3) two-layer forward, restructured:
//   cheb(x,W) = x@W0 - x@W2 + P(x@W1 + 2*P(x@W2)) + b,  P = edge scatter-sum
// P applied in output feature space (64 then 40 dims).
// Edge scatter -> CSR-by-dst gather (hierarchical scan build).
// Gather tables packed bf16x2 per dword, row stride 32 dwords (128B aligned):
//   one dword gather instruction serves TWO edges (lanes 0-31 edge0, 32-63
//   edge1) -> 2 line-requests/edge instead of 4, half the gather instrs.
// GEMM1: fp32 A via bf16 hi/lo split (3 MFMA); GEMM2: bf16 A exact (2 MFMA).
// ---------------------------------------------------------------------------

#define FIN1 128
#define HID 64
#define NCLS 40

typedef __attribute__((ext_vector_type(8))) short sx8;
typedef __attribute__((ext_vector_type(4))) float fx4;

__device__ inline unsigned short f2bf(float f) {
    unsigned u = __float_as_uint(f);
    unsigned r = (u + 0x7FFF + ((u >> 16) & 1)) >> 16;  // RNE
    return (unsigned short)r;
}
__device__ inline float bf2f(unsigned short h) {
    return __uint_as_float((unsigned)h << 16);
}
__device__ inline unsigned pack2bf(float a, float b) {
    return (unsigned)f2bf(a) | ((unsigned)f2bf(b) << 16);
}

__global__ void k_count(const int* __restrict__ dst, int E, int* __restrict__ count) {
    int e = blockIdx.x * blockDim.x + threadIdx.x;
    if (e < E) atomicAdd(&count[dst[e]], 1);
}

// ---- hierarchical exclusive scan over count[N] ----
template <int EPT>
__global__ __launch_bounds__(256) void k_scan_part(const int* __restrict__ count, int N,
                                                   int* __restrict__ partial) {
    __shared__ int ws[4];
    int t = threadIdx.x;
    int lane = t & 63, w = t >> 6;
    int idx0 = blockIdx.x * 256 * EPT + t * EPT;
    int s = 0;
#pragma unroll
    for (int i = 0; i < EPT; ++i) {
        int idx = idx0 + i;
        if (idx < N) s += count[idx];
    }
#pragma unroll
    for (int d = 1; d < 64; d <<= 1) s += __shfl_xor(s, d);
    if (lane == 0) ws[w] = s;
    __syncthreads();
    if (t == 0) partial[blockIdx.x] = ws[0] + ws[1] + ws[2] + ws[3];
}

__global__ __launch_bounds__(256) void k_scan_mid(int* __restrict__ partial, int nb) {
    __shared__ int s[256];
    int t = threadIdx.x;
    int orig = (t < nb) ? partial[t] : 0;
    s[t] = orig;
    __syncthreads();
    for (int d = 1; d < 256; d <<= 1) {
        int v = (t >= d) ? s[t - d] : 0;
        __syncthreads();
        s[t] += v;
        __syncthreads();
    }
    if (t < nb) partial[t] = s[t] - orig;  // exclusive
}

template <int EPT>
__global__ __launch_bounds__(256) void k_scan_final(const int* __restrict__ count, int N,
                                                    const int* __restrict__ partial,
                                                    int* __restrict__ row_ptr,
                                                    int* __restrict__ cursor,
                                                    float* __restrict__ dis) {
    __shared__ int wsum[4];
    int t = threadIdx.x;
    int lane = t & 63, w = t >> 6;
    int idx0 = blockIdx.x * 256 * EPT + t * EPT;
    int c[EPT];
    int s = 0;
#pragma unroll
    for (int i = 0; i < EPT; ++i) {
        int idx = idx0 + i;
        c[i] = (idx < N) ? count[idx] : 0;
        s += c[i];
    }
    int incl = s;
#pragma unroll
    for (int d = 1; d < 64; d <<= 1) {
        int u = __shfl_up(incl, d);
        if (lane >= d) incl += u;
    }
    if (lane == 63) wsum[w] = incl;
    __syncthreads();
    int woff = 0;
    for (int i = 0; i < w; ++i) woff += wsum[i];
    int off = partial[blockIdx.x] + woff + (incl - s);
#pragma unroll
    for (int i = 0; i < EPT; ++i) {
        int idx = idx0 + i;
        if (idx < N) {
            row_ptr[idx] = off;
            cursor[idx] = off;
            dis[idx] = (c[i] > 0) ? rsqrtf((float)c[i]) : 0.0f;
            off += c[i];
            if (idx == N - 1) row_ptr[N] = off;
        }
    }
}

__global__ void k_fill(const int* __restrict__ src, const int* __restrict__ dst, int E,
                       const float* __restrict__ dis, int* __restrict__ cursor,
                       int2* __restrict__ csrp) {
    int e = blockIdx.x * blockDim.x + threadIdx.x;
    if (e < E) {
        int s = src[e];
        int d = dst[e];
        int pos = atomicAdd(&cursor[d], 1);
        csrp[pos] = make_int2(s, __float_as_int(-dis[s] * dis[d]));
    }
}

// Pre-swizzle W[3][FIN][FOE] (fp32) into MFMA B-fragment layout, hi/lo bf16.
template <int NS, int T, int FIN, int FOE>
__global__ void k_wprep(const float* __restrict__ W, unsigned short* __restrict__ hi,
                        unsigned short* __restrict__ lo) {
    int idx = blockIdx.x * 256 + threadIdx.x;
    constexpr int total = NS * T * 64 * 8;
    if (idx >= total) return;
    int i = idx & 7;
    int l = (idx >> 3) & 63;
    int t = (idx >> 9) % T;
    int s = idx / (512 * T);
    int k = s * 32 + (l >> 4) * 8 + i;
    int col = t * 16 + (l & 15);
    float w = 0.0f;
    if (col < 3 * FOE) {
        int m = col / FOE;
        int c = col - m * FOE;
        w = W[((size_t)m * FIN + k) * FOE + c];
    }
    unsigned short h = f2bf(w);
    hi[idx] = h;
    lo[idx] = f2bf(w - bf2f(h));
}

// MFMA GEMM, fp32 A (hi/lo split, 3 MFMA): C{0,1,2} = A@W[m] (fp32, stride FOE);
// C2 additionally packed bf16 (ushort stride 64).
template <int FIN, int T, int NS, int FOE>
__global__ __launch_bounds__(256, 3) void k_gemm_mfma(
    const float* __restrict__ A, const unsigned short* __restrict__ Whi,
    const unsigned short* __restrict__ Wlo, float* __restrict__ C0,
    float* __restrict__ C1, float* __restrict__ C2,
    unsigned short* __restrict__ C2h, int N) {
    int tid = threadIdx.x;
    int w = tid >> 6, l = tid & 63;
    int row0 = blockIdx.x * 128 + w * 32;
    int rl = l & 15, kg = l >> 4;

    fx4 acc[2][T];
#pragma unroll
    for (int rt = 0; rt < 2; ++rt)
#pragma unroll
        for (int t = 0; t < T; ++t) acc[rt][t] = (fx4)0.0f;

    for (int s = 0; s < NS; ++s) {
        int k0 = s * 32 + kg * 8;
        sx8 ahi[2], alo[2];
#pragma unroll
        for (int rt = 0; rt < 2; ++rt) {
            int r = min(row0 + rt * 16 + rl, N - 1);
            const fx4* ap = (const fx4*)(A + (size_t)r * FIN + k0);
            fx4 a0 = ap[0];
            fx4 a1 = ap[1];
#pragma unroll
            for (int j = 0; j < 4; ++j) {
                unsigned short h0 = f2bf(a0[j]);
                unsigned short h1 = f2bf(a1[j]);
                ahi[rt][j] = (short)h0;
                ahi[rt][j + 4] = (short)h1;
                alo[rt][j] = (short)f2bf(a0[j] - bf2f(h0));
                alo[rt][j + 4] = (short)f2bf(a1[j] - bf2f(h1));
            }
        }
        const sx8* wh = (const sx8*)(Whi + ((size_t)(s * T) * 64 + l) * 8);
        const sx8* wl = (const sx8*)(Wlo + ((size_t)(s * T) * 64 + l) * 8);
#pragma unroll
        for (int t = 0; t < T; ++t) {
            sx8 bh = wh[t * 64];
            sx8 bl = wl[t * 64];
#pragma unroll
            for (int rt = 0; rt < 2; ++rt) {
                acc[rt][t] = __builtin_amdgcn_mfma_f32_16x16x32_bf16(ahi[rt], bh, acc[rt][t], 0, 0, 0);
                acc[rt][t] = __builtin_amdgcn_mfma_f32_16x16x32_bf16(ahi[rt], bl, acc[rt][t], 0, 0, 0);
                acc[rt][t] = __builtin_amdgcn_mfma_f32_16x16x32_bf16(alo[rt], bh, acc[rt][t], 0, 0, 0);
            }
        }
    }

#pragma unroll
    for (int rt = 0; rt < 2; ++rt)
#pragma unroll
        for (int t = 0; t < T; ++t) {
            int col = t * 16 + rl;
            int m = col / FOE;
            int cc = col - m * FOE;
            if (m < 3) {
                float* Cm = (m == 0) ? C0 : ((m == 1) ? C1 : C2);
#pragma unroll
                for (int j = 0; j < 4; ++j) {
                    int r = row0 + rt * 16 + kg * 4 + j;
                    if (r < N) {
                        Cm[(size_t)r * FOE + cc] = acc[rt][t][j];
                        if (m == 2) C2h[(size_t)r * 64 + cc] = f2bf(acc[rt][t][j]);
                    }
                }
            }
        }
}

// MFMA GEMM, bf16 A (exact, 2 MFMA): C{0,1,2} = A@W[m] (fp32, stride FOE);
// C2 additionally packed bf16 (ushort stride 64).
template <int FIN, int T, int NS, int FOE>
__global__ __launch_bounds__(256, 3) void k_gemm_mfma_bf(
    const unsigned short* __restrict__ A, const unsigned short* __restrict__ Whi,
    const unsigned short* __restrict__ Wlo, float* __restrict__ C0,
    float* __restrict__ C1, float* __restrict__ C2,
    unsigned short* __restrict__ C2h, int N) {
    int tid = threadIdx.x;
    int w = tid >> 6, l = tid & 63;
    int row0 = blockIdx.x * 128 + w * 32;
    int rl = l & 15, kg = l >> 4;

    fx4 acc[2][T];
#pragma unroll
    for (int rt = 0; rt < 2; ++rt)
#pragma unroll
        for (int t = 0; t < T; ++t) acc[rt][t] = (fx4)0.0f;

    for (int s = 0; s < NS; ++s) {
        int k0 = s * 32 + kg * 8;
        sx8 a[2];
#pragma unroll
        for (int rt = 0; rt < 2; ++rt) {
            int r = min(row0 + rt * 16 + rl, N - 1);
            a[rt] = *(const sx8*)(A + (size_t)r * FIN + k0);
        }
        const sx8* wh = (const sx8*)(Whi + ((size_t)(s * T) * 64 + l) * 8);
        const sx8* wl = (const sx8*)(Wlo + ((size_t)(s * T) * 64 + l) * 8);
#pragma unroll
        for (int t = 0; t < T; ++t) {
            sx8 bh = wh[t * 64];
            sx8 bl = wl[t * 64];
#pragma unroll
            for (int rt = 0; rt < 2; ++rt) {
                acc[rt][t] = __builtin_amdgcn_mfma_f32_16x16x32_bf16(a[rt], bh, acc[rt][t], 0, 0, 0);
                acc[rt][t] = __builtin_amdgcn_mfma_f32_16x16x32_bf16(a[rt], bl, acc[rt][t], 0, 0, 0);
            }
        }
    }

#pragma unroll
    for (int rt = 0; rt < 2; ++rt)
#pragma unroll
        for (int t = 0; t < T; ++t) {
            int col = t * 16 + rl;
            int m = col / FOE;
            int cc = col - m * FOE;
            if (m < 3) {
                float* Cm = (m == 0) ? C0 : ((m == 1) ? C1 : C2);
#pragma unroll
                for (int j = 0; j < 4; ++j) {
                    int r = row0 + rt * 16 + kg * 4 + j;
                    if (r < N) {
                        Cm[(size_t)r * FOE + cc] = acc[rt][t][j];
                        if (m == 2) C2h[(size_t)r * 64 + cc] = f2bf(acc[rt][t][j]);
                    }
                }
            }
        }
}

// CSR gather-prop, dual-edge packed form. One wave per dst node.
// Gather table: packed bf16x2 per dword, row stride 32 dwords (128B aligned).
// Lanes 0-31 gather edge e0's row, lanes 32-63 edge e1's row in ONE dword
// instruction (2 line-requests/edge). Lane c holds features (2c, 2c+1).
// Partial sums combined with shfl_xor(32) at the end.
// MODE 0: outh = packbf16(o0 + 2*acc)           (o0 fp32 stride F)
// MODE 1: outh = packbf16(relu(o0 - o1 + acc + bias))
// MODE 2: outf = log_softmax(o0 - o1 + acc + bias) over F classes (fp32)
template <int F, int MODE>
__global__ void k_prop(const int* __restrict__ row_ptr, const int2* __restrict__ csrp,
                       const unsigned* __restrict__ in,
                       const float* __restrict__ o0, const float* __restrict__ o1,
                       const float* __restrict__ bias,
                       unsigned* __restrict__ outh, float* __restrict__ outf, int N) {
    constexpr int FH = F / 2;
    int wid = (blockIdx.x * blockDim.x + threadIdx.x) >> 6;
    int lane = threadIdx.x & 63;
    if (wid >= N) return;
    int g = lane >> 5;   // edge slot within a pair
    int c = lane & 31;   // feature-pair index
    int beg = row_ptr[wid];
    int end = row_ptr[wid + 1];
    float ax = 0.0f, ay = 0.0f;
    for (int j = beg; j < end; j += 16) {
        int2 md = csrp[j + (lane & 15)];  // 16-edge metadata chunk, coalesced
#pragma unroll
        for (int t = 0; t < 8; ++t) {
            int idx = 2 * t + g;
            int s = __shfl(md.x, idx);
            float w = (j + idx < end) ? __int_as_float(__shfl(md.y, idx)) : 0.0f;
            unsigned v = in[(size_t)s * 32 + c];
            ax = fmaf(w, __uint_as_float(v << 16), ax);
            ay = fmaf(w, __uint_as_float(v & 0xffff0000u), ay);
        }
    }
    ax += __shfl_xor(ax, 32);
    ay += __shfl_xor(ay, 32);

    if (MODE == 0) {
        if (g == 0 && c < FH) {
            float2 o = ((const float2*)o0)[(size_t)wid * FH + c];
            outh[(size_t)wid * 32 + c] = pack2bf(o.x + 2.0f * ax, o.y + 2.0f * ay);
        }
    } else if (MODE == 1) {
        if (g == 0 && c < FH) {
            float2 o = ((const float2*)o0)[(size_t)wid * FH + c];
            float2 q = ((const float2*)o1)[(size_t)wid * FH + c];
            float2 b = ((const float2*)bias)[c];
            float z0 = fmaxf(o.x - q.x + ax + b.x, 0.0f);
            float z1 = fmaxf(o.y - q.y + ay + b.y, 0.0f);
            outh[(size_t)wid * 32 + c] = pack2bf(z0, z1);
        }
    } else {
        float z0 = -INFINITY, z1 = -INFINITY;
        if (g == 0 && c < FH) {
            float2 o = ((const float2*)o0)[(size_t)wid * FH + c];
            float2 q = ((const float2*)o1)[(size_t)wid * FH + c];
            float2 b = ((const float2*)bias)[c];
            z0 = o.x - q.x + ax + b.x;
            z1 = o.y - q.y + ay + b.y;
        }
        float m = fmaxf(z0, z1);
#pragma unroll
        for (int d = 32; d; d >>= 1) m = fmaxf(m, __shfl_xor(m, d));
        float e0 = (g == 0 && c < FH) ? expf(z0 - m) : 0.0f;
        float e1 = (g == 0 && c < FH) ? expf(z1 - m) : 0.0f;
        float l = e0 + e1;
#pragma unroll
        for (int d = 32; d; d >>= 1) l += __shfl_xor(l, d);
        if (g == 0 && c < FH) {
            float lg = m + logf(l);
            ((float2*)outf)[(size_t)wid * FH + c] = make_float2(z0 - lg, z1 - lg);
        }
    }
}

extern "C" void kernel_launch(void* const* d_in, const int* in_sizes, int n_in,
                              void* d_out, int out_size, void* d_ws, size_t ws_size,
                              hipStream_t stream) {
    const float* x = (const float*)d_in[0];
    const int* ei = (const int*)d_in[1];
    const float* W1 = (const float*)d_in[2];
    const float* b1 = (const float*)d_in[3];
    const float* W2 = (const float*)d_in[4];
    const float* b2 = (const float*)d_in[5];
    float* out = (float*)d_out;

    const int N = in_sizes[0] / FIN1;  // 100000
    const int E = in_sizes[1] / 2;     // 1600000
    const int* src = ei;
    const int* dst = ei + E;

    // workspace carve (256B aligned)
    char* p = (char*)d_ws;
    auto alloc = [&](size_t bytes) -> void* {
        void* r = (void*)p;
        p += (bytes + 255) & ~(size_t)255;
        return r;
    };
    int* count = (int*)alloc((size_t)N * 4);
    int* row_ptr = (int*)alloc((size_t)(N + 1) * 4);
    int* cursor = (int*)alloc((size_t)N * 4);
    float* dis = (float*)alloc((size_t)N * 4);
    int* partial = (int*)alloc(256 * 4);
    int2* csrp = (int2*)alloc(((size_t)E + 16) * 8);  // packed (src, norm) + pad
    float* buf0 = (float*)alloc((size_t)N * HID * 4);  // c0 / d0 (fp32)
    float* buf1 = (float*)alloc((size_t)N * HID * 4);  // ca / da (fp32)
    float* buf2 = (float*)alloc((size_t)N * HID * 4);  // cb / db (fp32)
    unsigned* buf2h = (unsigned*)alloc((size_t)N * 32 * 4);  // cb/db packed bf16x2
    unsigned* buf3h = (unsigned*)alloc((size_t)N * 32 * 4);  // s/s2 packed bf16x2
    unsigned* buf4h = (unsigned*)alloc((size_t)N * 32 * 4);  // h packed bf16x2
    // W fragment buffers (hi/lo bf16, B-frag layout)
    constexpr int W1FRAG = 4 * 12 * 64 * 8;  // 24576
    constexpr int W2FRAG = 2 * 8 * 64 * 8;   // 8192
    unsigned short* wf1h = (unsigned short*)alloc((size_t)W1FRAG * 2);
    unsigned short* wf1l = (unsigned short*)alloc((size_t)W1FRAG * 2);
    unsigned short* wf2h = (unsigned short*)alloc((size_t)W2FRAG * 2);
    unsigned short* wf2l = (unsigned short*)alloc((size_t)W2FRAG * 2);

    const int be = (E + 255) / 256;
    const int bg = (N + 127) / 128;       // MFMA gemm blocks (BM=128)
    const int bp = (N * 64 + 255) / 256;  // one wave per node
    constexpr int EPB = 256 * 8;
    const int nb = (N + EPB - 1) / EPB;   // 49 blocks for N=100000

    // ---- W fragment prep (independent of graph) ----
    k_wprep<4, 12, FIN1, HID><<<(W1FRAG + 255) / 256, 256, 0, stream>>>(W1, wf1h, wf1l);
    k_wprep<2, 8, HID, NCLS><<<(W2FRAG + 255) / 256, 256, 0, stream>>>(W2, wf2h, wf2l);

    // ---- graph structure: degree, CSR, norm ----
    hipMemsetAsync(count, 0, (size_t)N * 4, stream);
    hipMemsetAsync(csrp + E, 0, (size_t)16 * 8, stream);  // zero pad records
    k_count<<<be, 256, 0, stream>>>(dst, E, count);
    k_scan_part<8><<<nb, 256, 0, stream>>>(count, N, partial);
    k_scan_mid<<<1, 256, 0, stream>>>(partial, nb);
    k_scan_final<8><<<nb, 256, 0, stream>>>(count, N, partial, row_ptr, cursor, dis);
    k_fill<<<be, 256, 0, stream>>>(src, dst, E, dis, cursor, csrp);

    // ---- layer 1: x[N,128] -> h[N,64] ----
    k_gemm_mfma<FIN1, 12, 4, HID><<<bg, 256, 0, stream>>>(
        x, wf1h, wf1l, buf0, buf1, buf2, (unsigned short*)buf2h, N);
    // s = ca + 2*P(cb)
    k_prop<HID, 0><<<bp, 256, 0, stream>>>(row_ptr, csrp, buf2h, buf1, nullptr, nullptr,
                                           buf3h, nullptr, N);
    // h = relu(c0 - cb + P(s) + b1)
    k_prop<HID, 1><<<bp, 256, 0, stream>>>(row_ptr, csrp, buf3h, buf0, buf2, b1,
                                           buf4h, nullptr, N);

    // ---- layer 2: h[N,64] -> out[N,40] ----
    k_gemm_mfma_bf<HID, 8, 2, NCLS><<<bg, 256, 0, stream>>>(
        (const unsigned short*)buf4h, wf2h, wf2l, buf0, buf1, buf2,
        (unsigned short*)buf2h, N);
    // s2 = da + 2*P(db)
    k_prop<NCLS, 0><<<bp, 256, 0, stream>>>(row_ptr, csrp, buf2h, buf1, nullptr, nullptr,
                                            buf3h, nullptr, N);
    // out = log_softmax(d0 - db + P(s2) + b2)
    k_prop<NCLS, 2><<<bp, 256, 0, stream>>>(row_ptr, csrp, buf3h, buf0, buf2, b2,
                                            nullptr, out, N);
}